// Round 8
// baseline (99.849 us; speedup 1.0000x reference)
//
#include <hip/hip_runtime.h>

#define B 8
#define N 8192
#define M 2048
#define NITER 4
#define BASE_ALPHA 0.1f
#define MARGIN 0.005f          // >> fp slack (~1e-6) on the NN-invariance bound
#define CAP 16                 // candidate-list capacity (expected count ~1-3)

#define NTHR 1024              // 16 waves (iter0)
#define NPT 32                 // point-lanes per split
#define NSPLIT 32              // j-splits per block
#define JS (M / NSPLIT)        // 64 y's per split
#define JQ (JS / 4)            // 16 j-quads per split
#define PT 8                   // points per thread
#define PPB (NPT * PT)         // 256 points per block
#define NBLK (B * N / PPB)     // 256 blocks

#define LTHR 256               // light/final kernels: 256 blocks x 256 thr
#define BPB 32                 // blocks per batch (light grid)

// ws: pos4 float4[B*N] @0; aux uint2[B*N] @1M (bits(md), logical idx);
// mask u32[B*N] @1.5M; cnt u32[B*N] @1.75M (>CAP => fallback);
// cand u16[B*N][CAP] @2M (ascending j); slot0 @4M, slot1 @4M+4K (double-
// buffered batch-max across kernel boundaries — the R5 structure, absmax 0.0).
// NN-invariance: computed argmin at iters 1-3 lies in {j: dist_0(j) <= d_0 +
// MARGIN}: mv = sum(alpha_i*d_i), NN-dist at step u = d_0 - mv (move is
// exactly toward NN; triangle ineq lower-bounds all others), excluded j loses
// by >= MARGIN >> fp slack.
// R8: iter0's collection had a 16-way LDS bank conflict (SoA-by-4 layout puts
// each split's 64 j's in 4 banks; 128 words ≡ 0 mod 32). Fix: split-major
// float4 sC[j], lane l reads sC[s*64+l] = coalesced b128. Also: argmin folded
// into collection (pass-2 deleted; lex (t,j) wave-reduce = first-argmin;
// min-value bits == tstar bits since fmin is exact over the same multiset).
#define OFF_AUX   (1024 * 1024)
#define OFF_MASK  (1536 * 1024)
#define OFF_CNT   (1792 * 1024)
#define OFF_CANDL (2048 * 1024)
#define OFF_SLOT0 (4096 * 1024)
#define OFF_SLOT1 (4100 * 1024)

typedef float f2 __attribute__((ext_vector_type(2)));

// ---------------- iter 0: full scan + argmin + candidate lists --------------
__global__ __launch_bounds__(NTHR, 4) void iter_kernel(const float* __restrict__ pred,
                                                       const float* __restrict__ partial,
                                                       float4* __restrict__ pos4,
                                                       uint2* __restrict__ aux,
                                                       unsigned int* __restrict__ maskbuf,
                                                       unsigned int* __restrict__ gcnt,
                                                       unsigned short* __restrict__ gcand,
                                                       float* __restrict__ slots) {
    __shared__ float4 sX[M / 4], sY[M / 4], sZ[M / 4], sW[M / 4];  // 32 KB (pass-1)
    __shared__ float4 sC[M];                                       // 32 KB split-major (collection)
    __shared__ float smint[NSPLIT][PPB];                           // 32 KB
    __shared__ float4 lpos[PPB];                                   // 4 KB
    __shared__ float thrsh[PPB];                                   // 1 KB
    __shared__ unsigned int smask[PPB];                            // 1 KB
    __shared__ float pmd[PPB];                                     // 1 KB
    __shared__ float redbuf[4];

    const int tid = threadIdx.x;
    const int b = blockIdx.x >> 5;
    const int blk = blockIdx.x & 31;
    const int gp0 = b * N + blk * PPB;

    // Build SoA tile + split-major tile. (-2y)*x bit-equal to reference's
    // (-2x)*y. Each |y|^2 computed ONCE and stored into both tiles.
    const float* pa = partial + b * M * 3;
    if (tid < M / 4) {
        int sp = tid & 31, jq = tid >> 5;
        const float* p0 = pa + (sp * JS + jq * 4) * 3;
        float a0 = p0[0], a1 = p0[1],  a2 = p0[2];
        float b0 = p0[3], b1 = p0[4],  b2 = p0[5];
        float c0 = p0[6], c1 = p0[7],  c2 = p0[8];
        float d0 = p0[9], d1 = p0[10], d2 = p0[11];
        float wa = a0 * a0 + a1 * a1 + a2 * a2;
        float wb = b0 * b0 + b1 * b1 + b2 * b2;
        float wc = c0 * c0 + c1 * c1 + c2 * c2;
        float wd = d0 * d0 + d1 * d1 + d2 * d2;
        sX[tid] = make_float4(-2.f * a0, -2.f * b0, -2.f * c0, -2.f * d0);
        sY[tid] = make_float4(-2.f * a1, -2.f * b1, -2.f * c1, -2.f * d1);
        sZ[tid] = make_float4(-2.f * a2, -2.f * b2, -2.f * c2, -2.f * d2);
        sW[tid] = make_float4(wa, wb, wc, wd);
        int j0 = sp * JS + jq * 4;
        sC[j0 + 0] = make_float4(-2.f * a0, -2.f * a1, -2.f * a2, wa);
        sC[j0 + 1] = make_float4(-2.f * b0, -2.f * b1, -2.f * b2, wb);
        sC[j0 + 2] = make_float4(-2.f * c0, -2.f * c1, -2.f * c2, wc);
        sC[j0 + 3] = make_float4(-2.f * d0, -2.f * d1, -2.f * d2, wd);
    }

    // Owners: refined_0 = pred.
    if (tid < PPB) {
        const int p = gp0 + tid;
        const float* pp = pred + (unsigned long long)p * 3;
        float rx = pp[0], ry = pp[1], rz = pp[2];
        float w = rx * rx + ry * ry + rz * rz;
        lpos[tid] = make_float4(rx, ry, rz, w);
        pos4[p] = make_float4(rx, ry, rz, w);
    }
    __syncthreads();

    const int split = tid >> 5;                    // 0..31 (uniform per half-wave)
    const int pt = tid & 31;

    // ---- pass 1: packed-f32 per-split min ----
    f2 sx[PT], sy[PT], sz[PT];
    #pragma unroll
    for (int k = 0; k < PT; ++k) {
        float4 r = lpos[pt + k * NPT];
        sx[k] = (f2){r.x, r.x}; sy[k] = (f2){r.y, r.y}; sz[k] = (f2){r.z, r.z};
    }
    f2 acc[PT];
    #pragma unroll
    for (int k = 0; k < PT; ++k) acc[k] = (f2){3.402823466e+38f, 3.402823466e+38f};

    #pragma unroll 2
    for (int jq = 0; jq < JQ; ++jq) {
        float4 qx = sX[jq * 32 + split], qy = sY[jq * 32 + split];
        float4 qz = sZ[jq * 32 + split], qw = sW[jq * 32 + split];
        f2 qx01 = (f2){qx.x, qx.y}, qx23 = (f2){qx.z, qx.w};
        f2 qy01 = (f2){qy.x, qy.y}, qy23 = (f2){qy.z, qy.w};
        f2 qz01 = (f2){qz.x, qz.y}, qz23 = (f2){qz.z, qz.w};
        f2 qw01 = (f2){qw.x, qw.y}, qw23 = (f2){qw.z, qw.w};
        #pragma unroll
        for (int k = 0; k < PT; ++k) {
            f2 t01 = __builtin_elementwise_fma(sx[k], qx01,
                     __builtin_elementwise_fma(sy[k], qy01,
                     __builtin_elementwise_fma(sz[k], qz01, qw01)));
            f2 t23 = __builtin_elementwise_fma(sx[k], qx23,
                     __builtin_elementwise_fma(sy[k], qy23,
                     __builtin_elementwise_fma(sz[k], qz23, qw23)));
            acc[k] = __builtin_elementwise_min(acc[k],
                     __builtin_elementwise_min(t01, t23));     // exact, order-invariant
        }
    }
    #pragma unroll
    for (int k = 0; k < PT; ++k)
        smint[split][pt + k * NPT] = fminf(acc[k].x, acc[k].y);
    __syncthreads();

    // ---- owners: tstar -> threshold + split mask (no pass-2 here) ----
    if (tid < PPB) {
        float tstar = 3.402823466e+38f;
        #pragma unroll
        for (int s = 0; s < NSPLIT; ++s) tstar = fminf(tstar, smint[s][tid]);
        const float4 f4 = lpos[tid];
        const float md = sqrtf(fmaxf(f4.w + tstar, 0.0f));
        float mdm = md + MARGIN;
        float thr = fmaf(mdm, mdm, -f4.w);         // dist<=md+MARGIN <=> t<=thr
        thrsh[tid] = thr;
        unsigned int mask = 0u;
        #pragma unroll
        for (int s = 0; s < NSPLIT; ++s)
            if (smint[s][tid] <= thr) mask |= (1u << s);
        smask[tid] = mask;                         // always contains the best split
        maskbuf[gp0 + tid] = mask;
    }
    __syncthreads();

    // ---- collection + argmin: wave-per-point, uniform, conflict-free ----
    // Per masked split s (wave-uniform ctz loop), lane l evaluates j=s*64+l
    // via sC (b128, consecutive -> no bank conflicts). Lane tracks lex (t,j)
    // (ascending j per lane -> strict < = first); 6-step shfl_xor lexmin ->
    // global first-argmin over masked splits == global first-argmin (unmasked
    // splits have min > thr >= tstar). Candidates compacted ascending-j.
    {
        const int lane = tid & 63;
        const int wv = tid >> 6;                   // 0..15
        const unsigned long long lmask = (1ull << lane) - 1ull;
        for (int q0 = 0; q0 < 16; ++q0) {
            int q = wv * 16 + q0;
            float4 f4 = lpos[q];                   // broadcast reads
            float thr = thrsh[q];
            unsigned int m = smask[q];             // wave-uniform
            int cnt = 0;
            unsigned long long cb = (unsigned long long)(gp0 + q) * CAP;
            float bt = 3.402823466e+38f; int bj = 0;
            while (m) {
                int s = __builtin_ctz(m); m &= m - 1;
                int j = s * JS + lane;
                float4 c = sC[j];
                float t = fmaf(f4.x, c.x, fmaf(f4.y, c.y, fmaf(f4.z, c.z, c.w)));
                if (t < bt) { bt = t; bj = j; }
                bool hit = (t <= thr);
                unsigned long long bal = __ballot(hit);
                int pos = cnt + (int)__popcll(bal & lmask);
                if (hit && pos < CAP)
                    gcand[cb + pos] = (unsigned short)j;
                cnt += (int)__popcll(bal);
            }
            #pragma unroll
            for (int o = 32; o > 0; o >>= 1) {
                float to = __shfl_xor(bt, o);
                int jo = __shfl_xor(bj, o);
                if (to < bt || (to == bt && jo < bj)) { bt = to; bj = jo; }
            }
            if (lane == 0) {
                gcnt[gp0 + q] = (unsigned int)cnt;
                float md = sqrtf(fmaxf(f4.w + bt, 0.0f));
                aux[gp0 + q] = make_uint2(__float_as_uint(md), (unsigned int)bj);
                pmd[q] = md;
            }
        }
    }
    __syncthreads();

    // ---- per-block batch-max partial -> slots (R5 structure) ----
    if (tid < PPB) {
        float wm = pmd[tid];
        #pragma unroll
        for (int o = 32; o > 0; o >>= 1) wm = fmaxf(wm, __shfl_down(wm, o));
        if ((tid & 63) == 0) redbuf[tid >> 6] = wm;
    }
    __syncthreads();
    if (tid == 0)
        slots[b * BPB + blk] = fmaxf(fmaxf(redbuf[0], redbuf[1]),
                                     fmaxf(redbuf[2], redbuf[3]));
}

// Rare fallback: masked-split ascending-j scan from global partial
// (strict < = first-argmin; -2y / |y|^2 recompute chain).
__device__ __attribute__((noinline)) void nn_fallback(float x, float y, float z,
                                                      unsigned int mk,
                                                      const float* __restrict__ pa,
                                                      float& bt_out, int& bj_out) {
    float bt = 3.402823466e+38f; int bj = 0;
    unsigned int m = mk;
    while (m) {
        int s = __builtin_ctz(m); m &= m - 1;
        int jb = s * JS;
        for (int jj = 0; jj < JS; ++jj) {
            int j = jb + jj;
            const float* py = pa + j * 3;
            float y0 = py[0], y1 = py[1], y2 = py[2];
            float qx = -2.f * y0, qy = -2.f * y1, qz = -2.f * y2;
            float qw = y0 * y0 + y1 * y1 + y2 * y2;
            float t = fmaf(x, qx, fmaf(y, qy, fmaf(z, qz, qw)));
            if (t < bt) { bt = t; bj = j; }
        }
    }
    bt_out = bt; bj_out = bj;
}

// ---------------- iters 1..3: update + candidate NN (R5, absmax-0 path) -----
__global__ __launch_bounds__(LTHR) void light_kernel(const float* __restrict__ partial,
                                                     float4* __restrict__ pos4,
                                                     uint2* __restrict__ aux,
                                                     const unsigned int* __restrict__ maskbuf,
                                                     const unsigned int* __restrict__ gcnt,
                                                     const unsigned short* __restrict__ gcand,
                                                     const float* __restrict__ slots_in,
                                                     float* __restrict__ slots_out) {
    __shared__ float redbuf[4];
    __shared__ float mxsh;

    const int tid = threadIdx.x;
    const int p = blockIdx.x * LTHR + tid;         // batch uniform per block
    const int b = p >> 13;
    const int blk = blockIdx.x & 31;
    const float* pa = partial + b * M * 3;

    if (tid < 64) {
        float v = slots_in[b * BPB + (tid & 31)];
        #pragma unroll
        for (int o = 16; o > 0; o >>= 1) v = fmaxf(v, __shfl_xor(v, o));
        if (tid == 0) mxsh = v;
    }
    __syncthreads();

    float4 f = pos4[p];
    uint2 a = aux[p];
    float md = __uint_as_float(a.x);
    unsigned int cnt = gcnt[p];

    // update (verbatim chains; raw partial read == -0.5*(-2y) bits)
    const float* py = pa + (int)a.y * 3;
    float y0 = py[0], y1 = py[1], y2 = py[2];
    float inv = 1.0f / (mxsh + 1e-6f);
    float alpha = BASE_ALPHA * (2.0f - md * inv);
    float nx = fmaf(alpha, y0 - f.x, f.x);
    float ny = fmaf(alpha, y1 - f.y, f.y);
    float nz = fmaf(alpha, y2 - f.z, f.z);
    float w = nx * nx + ny * ny + nz * nz;
    pos4[p] = make_float4(nx, ny, nz, w);

    // NN over candidate list (ascending j; lex (t,j) min == first-argmin)
    float bt = 3.402823466e+38f; int bj = 0;
    if (cnt <= CAP) {
        const unsigned short* cp = gcand + (unsigned long long)p * CAP;
        for (unsigned int c = 0; c < cnt; ++c) {
            int j = cp[c];
            const float* pj = pa + j * 3;
            float a0 = pj[0], a1 = pj[1], a2 = pj[2];
            float qx = -2.f * a0, qy = -2.f * a1, qz = -2.f * a2;
            float qw = a0 * a0 + a1 * a1 + a2 * a2;
            float t = fmaf(nx, qx, fmaf(ny, qy, fmaf(nz, qz, qw)));
            if (t < bt || (t == bt && j < bj)) { bt = t; bj = j; }
        }
    } else {
        nn_fallback(nx, ny, nz, maskbuf[p], pa, bt, bj);
    }
    float mdn = sqrtf(fmaxf(w + bt, 0.0f));
    aux[p] = make_uint2(__float_as_uint(mdn), (unsigned int)bj);

    float wm = mdn;
    #pragma unroll
    for (int o = 32; o > 0; o >>= 1) wm = fmaxf(wm, __shfl_down(wm, o));
    if ((tid & 63) == 0) redbuf[tid >> 6] = wm;
    __syncthreads();
    if (tid == 0)
        slots_out[b * BPB + blk] = fmaxf(fmaxf(redbuf[0], redbuf[1]),
                                         fmaxf(redbuf[2], redbuf[3]));
}

__global__ __launch_bounds__(LTHR) void final_kernel(const float* __restrict__ partial,
                                                     const float4* __restrict__ pos4,
                                                     const uint2* __restrict__ aux,
                                                     const float* __restrict__ slots,
                                                     float* __restrict__ out) {
    __shared__ float mxsh;
    const int p = blockIdx.x * LTHR + threadIdx.x; // batch uniform per block
    const int b = p >> 13;
    if (threadIdx.x < 64) {
        float v = slots[b * BPB + (threadIdx.x & 31)];
        #pragma unroll
        for (int o = 16; o > 0; o >>= 1) v = fmaxf(v, __shfl_xor(v, o));
        if (threadIdx.x == 0) mxsh = v;
    }
    __syncthreads();
    float4 f = pos4[p];
    uint2 a = aux[p];
    float md = __uint_as_float(a.x);
    const float* py = partial + ((unsigned long long)(b * M + (int)a.y)) * 3;
    float y0 = py[0], y1 = py[1], y2 = py[2];      // same bits as -0.5*(-2y)
    float inv = 1.0f / (mxsh + 1e-6f);
    float alpha = BASE_ALPHA * (2.0f - md * inv);
    float* po = out + (unsigned long long)p * 3;
    po[0] = fmaf(alpha, y0 - f.x, f.x);
    po[1] = fmaf(alpha, y1 - f.y, f.y);
    po[2] = fmaf(alpha, y2 - f.z, f.z);
}

extern "C" void kernel_launch(void* const* d_in, const int* in_sizes, int n_in,
                              void* d_out, int out_size, void* d_ws, size_t ws_size,
                              hipStream_t stream) {
    const float* pred = (const float*)d_in[0];
    const float* partial = (const float*)d_in[1];
    char* ws = (char*)d_ws;
    float4* pos4 = (float4*)ws;
    uint2* aux = (uint2*)(ws + OFF_AUX);
    unsigned int* maskb = (unsigned int*)(ws + OFF_MASK);
    unsigned int* gcnt = (unsigned int*)(ws + OFF_CNT);
    unsigned short* gcand = (unsigned short*)(ws + OFF_CANDL);
    float* slot0 = (float*)(ws + OFF_SLOT0);
    float* slot1 = (float*)(ws + OFF_SLOT1);
    float* out = (float*)d_out;

    hipLaunchKernelGGL(iter_kernel, dim3(NBLK), dim3(NTHR), 0, stream,
                       pred, partial, pos4, aux, maskb, gcnt, gcand, slot0);
    hipLaunchKernelGGL(light_kernel, dim3(B * N / LTHR), dim3(LTHR), 0, stream,
                       partial, pos4, aux, maskb, gcnt, gcand, slot0, slot1);
    hipLaunchKernelGGL(light_kernel, dim3(B * N / LTHR), dim3(LTHR), 0, stream,
                       partial, pos4, aux, maskb, gcnt, gcand, slot1, slot0);
    hipLaunchKernelGGL(light_kernel, dim3(B * N / LTHR), dim3(LTHR), 0, stream,
                       partial, pos4, aux, maskb, gcnt, gcand, slot0, slot1);
    hipLaunchKernelGGL(final_kernel, dim3(B * N / LTHR), dim3(LTHR), 0, stream,
                       partial, pos4, aux, slot1, out);
}